// Round 2
// baseline (642.394 us; speedup 1.0000x reference)
//
#include <hip/hip_runtime.h>
#include <hip/hip_bf16.h>

#define B_DIM 4096
#define UNITS_DIM 2048
#define K_DIM 4096   // INP + UNITS concatenated
#define M_DIM 8192   // 4 gates * UNITS, interleaved n = u*4 + g

typedef __bf16 bf16x8 __attribute__((ext_vector_type(8)));
typedef float f32x4 __attribute__((ext_vector_type(4)));

#define AS1C(p) ((const __attribute__((address_space(1))) void*)(p))
#define AS3(p)  ((__attribute__((address_space(3))) void*)(p))

__device__ __forceinline__ float fast_sigmoid(float x) {
    return 1.0f / (1.0f + __expf(-x));
}
__device__ __forceinline__ float fast_tanh(float x) {
    return 2.0f / (1.0f + __expf(-2.0f * x)) - 1.0f;
}

// ---------------------------------------------------------------------------
// Kernel 1: Abf[b][k] = bf16( k<2048 ? x[b][k] : pre_h[b][k-2048] )
// ---------------------------------------------------------------------------
__global__ void convert_act(const float* __restrict__ pre_h,
                            const float* __restrict__ x,
                            __hip_bfloat16* __restrict__ Abf) {
    const long long idx = (long long)blockIdx.x * blockDim.x + threadIdx.x;
    const long long e = idx * 8;
    const int b = (int)(e >> 12);
    const int k = (int)(e & 4095);
    const float* src = (k < UNITS_DIM)
        ? (x + (long long)b * UNITS_DIM + k)
        : (pre_h + (long long)b * UNITS_DIM + (k - UNITS_DIM));
    float4 f0 = ((const float4*)src)[0];
    float4 f1 = ((const float4*)src)[1];
    union { __hip_bfloat16 h[8]; uint4 u4; } p;
    p.h[0] = __float2bfloat16(f0.x); p.h[1] = __float2bfloat16(f0.y);
    p.h[2] = __float2bfloat16(f0.z); p.h[3] = __float2bfloat16(f0.w);
    p.h[4] = __float2bfloat16(f1.x); p.h[5] = __float2bfloat16(f1.y);
    p.h[6] = __float2bfloat16(f1.z); p.h[7] = __float2bfloat16(f1.w);
    *(uint4*)(Abf + e) = p.u4;
}

// ---------------------------------------------------------------------------
// Kernel 2: Bbf[n][k], n = u*4+g:  k<2048 ? W[g][u][k] : U[g][u][k-2048]
// ---------------------------------------------------------------------------
__global__ void convert_wu(const float* __restrict__ W,
                           const float* __restrict__ U,
                           __hip_bfloat16* __restrict__ Bbf) {
    const long long idx = (long long)blockIdx.x * blockDim.x + threadIdx.x;
    const long long e = idx * 8;
    const int n = (int)(e >> 12);
    const int k = (int)(e & 4095);
    const int u = n >> 2;
    const int g = n & 3;
    const float* src = (k < UNITS_DIM)
        ? (W + ((long long)g * UNITS_DIM + u) * UNITS_DIM + k)
        : (U + ((long long)g * UNITS_DIM + u) * UNITS_DIM + (k - UNITS_DIM));
    float4 f0 = ((const float4*)src)[0];
    float4 f1 = ((const float4*)src)[1];
    union { __hip_bfloat16 h[8]; uint4 u4; } p;
    p.h[0] = __float2bfloat16(f0.x); p.h[1] = __float2bfloat16(f0.y);
    p.h[2] = __float2bfloat16(f0.z); p.h[3] = __float2bfloat16(f0.w);
    p.h[4] = __float2bfloat16(f1.x); p.h[5] = __float2bfloat16(f1.y);
    p.h[6] = __float2bfloat16(f1.z); p.h[7] = __float2bfloat16(f1.w);
    *(uint4*)(Bbf + e) = p.u4;
}

// ---------------------------------------------------------------------------
// Kernel 3: 256x256-tile bt-GEMM, 8-phase fine-interleaved schedule
// (4 phases per BK=64 K-tile, 2 K-tiles per LDS double-buffer pair).
//
// LDS per operand: [2 bufs][2 k-halves][256 rows][32 cols] bf16 = 64 KB.
// Half-tile = one k-half slab of one operand (256x32 = 16 KB = 2 gload/thr).
//
// Phase p of tile k (quadrant = (mi-half, kk)):
//   P0: ds_read AF[0-3][k0] + BF[0-3][k0] (8) | stage A-khi(k+1) | MFMA Q0
//   P1: ds_read AF[4-7][k0]             (4) | stage B-klo(k+2) | MFMA Q1
//   P2: ds_read AF[0-3][k1] + BF[0-3][k1] (8) | stage A-klo(k+2) | MFMA Q2
//   P3: ds_read AF[4-7][k1]             (4) | stage B-khi(k+2) | vmcnt(6) | Q3
// Each phase: reads+stage -> barrier -> lgkmcnt(0)+sched_barrier ->
//             setprio(1) 16 MFMA setprio(0) -> barrier.
//
// WAR safety: B-klo consumed end-P0, A-klo end-P1, B-khi end-P2, A-khi
// end-P3 (all waves, via the lgkmcnt(0)-before-MFMA + barrier#2). Each
// stage targets the region consumed exactly one phase earlier.
// vmcnt(6) once per tile keeps 3 half-tiles (6 loads) in flight; never
// drains to 0 until the last 2 of 64 K-tiles.
//
// LDS swizzle (both sides): row r's 4 chunks of 8 bf16 permuted by
// c ^ ((r>>1)&3) -> 2-way bank aliasing only (free). gload_lds dest stays
// linear; the GLOBAL source column is pre-swizzled.
// ---------------------------------------------------------------------------
__global__ __launch_bounds__(512, 2) void lstm_gemm(
    const __hip_bfloat16* __restrict__ Wc,   // 8192 x 4096 (A operand)
    const __hip_bfloat16* __restrict__ Ac,   // 4096 x 4096 (B operand)
    const float* __restrict__ pre_c,         // 4096 x 2048
    float* __restrict__ out)                 // (2, 4096, 2048)
{
    __shared__ __hip_bfloat16 As[32768];  // 2 x 2 x 256 x 32
    __shared__ __hip_bfloat16 Bs[32768];

    const int tid  = threadIdx.x;
    const int lane = tid & 63;
    const int wave = tid >> 6;

    // XCD-aware bijective swizzle (512 % 8 == 0)
    const int bid  = blockIdx.x;
    const int wgid = (bid & 7) * 64 + (bid >> 3);
    const int m_base = (wgid & 31) * 256;
    const int n_base = (wgid >> 5) * 256;

    const int wm  = (wave >> 2) * 128;   // 2 waves in M
    const int wn  = (wave & 3) * 64;     // 4 waves in N
    const int l15 = lane & 15;
    const int lq  = lane >> 4;
    const int key = (l15 >> 1) & 3;

    // frag read offsets (elements): + mi*512 + kk*8192 + buf*16384
    const int aro = (wm + l15) * 32 + ((lq ^ key) * 8);
    const int bro = (wn + l15) * 32 + ((lq ^ key) * 8);

    // staging: thread t -> slab row t>>2 (and +128), LDS chunk t&3 (linear
    // dest t*16B); fetch pre-swizzled global chunk (t&3) ^ ((t>>3)&3).
    const int gc = (((tid & 3) ^ ((tid >> 3) & 3)) * 8);
    const __hip_bfloat16* wg0 = Wc + (size_t)(m_base + (tid >> 2)) * K_DIM + gc;
    const __hip_bfloat16* ag0 = Ac + (size_t)(n_base + (tid >> 2)) * K_DIM + gc;

#define STAGE_A(T, KK) do {                                                    \
        const int b_ = ((T) & 1) * 16384 + (KK) * 8192;                        \
        const size_t ko_ = (size_t)(T) * 64 + (KK) * 32;                       \
        __builtin_amdgcn_global_load_lds(AS1C(wg0 + ko_),                      \
            AS3(As + b_ + tid * 8), 16, 0, 0);                                 \
        __builtin_amdgcn_global_load_lds(AS1C(wg0 + (size_t)128 * K_DIM + ko_),\
            AS3(As + b_ + 4096 + tid * 8), 16, 0, 0);                          \
    } while (0)
#define STAGE_B(T, KK) do {                                                    \
        const int b_ = ((T) & 1) * 16384 + (KK) * 8192;                        \
        const size_t ko_ = (size_t)(T) * 64 + (KK) * 32;                       \
        __builtin_amdgcn_global_load_lds(AS1C(ag0 + ko_),                      \
            AS3(Bs + b_ + tid * 8), 16, 0, 0);                                 \
        __builtin_amdgcn_global_load_lds(AS1C(ag0 + (size_t)128 * K_DIM + ko_),\
            AS3(Bs + b_ + 4096 + tid * 8), 16, 0, 0);                          \
    } while (0)

#define PHASE_SYNC() do {                                                      \
        __builtin_amdgcn_s_barrier();                                          \
        asm volatile("s_waitcnt lgkmcnt(0)" ::: "memory");                     \
        __builtin_amdgcn_sched_barrier(0);                                     \
    } while (0)

    f32x4 acc[8][4] = {};

    // prologue: tile0 all 4 halves + tile1 first 3, order B-klo,A-klo,B-khi,A-khi
    STAGE_B(0, 0); STAGE_A(0, 0); STAGE_B(0, 1); STAGE_A(0, 1);
    STAGE_B(1, 0); STAGE_A(1, 0); STAGE_B(1, 1);
    asm volatile("s_waitcnt vmcnt(6)" ::: "memory");   // tile 0 landed
    __builtin_amdgcn_s_barrier();

    for (int k = 0; k < 64; ++k) {
        const int buf = (k & 1) * 16384;
        const __hip_bfloat16* Ab = As + buf + aro;
        const __hip_bfloat16* Bb = Bs + buf + bro;
        bf16x8 af[4], bfv[4];

        // ---- P0: quadrant (mi 0-3, kk0) ----
#pragma unroll
        for (int mi = 0; mi < 4; ++mi) af[mi] = *(const bf16x8*)(Ab + mi * 512);
#pragma unroll
        for (int ni = 0; ni < 4; ++ni) bfv[ni] = *(const bf16x8*)(Bb + ni * 512);
        if (k <= 62) STAGE_A(k + 1, 1);
        PHASE_SYNC();
        __builtin_amdgcn_s_setprio(1);
#pragma unroll
        for (int mi = 0; mi < 4; ++mi)
#pragma unroll
            for (int ni = 0; ni < 4; ++ni)
                acc[mi][ni] = __builtin_amdgcn_mfma_f32_16x16x32_bf16(
                    af[mi], bfv[ni], acc[mi][ni], 0, 0, 0);
        __builtin_amdgcn_s_setprio(0);
        __builtin_amdgcn_s_barrier();

        // ---- P1: quadrant (mi 4-7, kk0) ----
#pragma unroll
        for (int mi = 0; mi < 4; ++mi)
            af[mi] = *(const bf16x8*)(Ab + (4 + mi) * 512);
        if (k <= 61) STAGE_B(k + 2, 0);
        PHASE_SYNC();
        __builtin_amdgcn_s_setprio(1);
#pragma unroll
        for (int mi = 0; mi < 4; ++mi)
#pragma unroll
            for (int ni = 0; ni < 4; ++ni)
                acc[4 + mi][ni] = __builtin_amdgcn_mfma_f32_16x16x32_bf16(
                    af[mi], bfv[ni], acc[4 + mi][ni], 0, 0, 0);
        __builtin_amdgcn_s_setprio(0);
        __builtin_amdgcn_s_barrier();

        // ---- P2: quadrant (mi 0-3, kk1) ----
#pragma unroll
        for (int mi = 0; mi < 4; ++mi)
            af[mi] = *(const bf16x8*)(Ab + 8192 + mi * 512);
#pragma unroll
        for (int ni = 0; ni < 4; ++ni)
            bfv[ni] = *(const bf16x8*)(Bb + 8192 + ni * 512);
        if (k <= 61) STAGE_A(k + 2, 0);
        PHASE_SYNC();
        __builtin_amdgcn_s_setprio(1);
#pragma unroll
        for (int mi = 0; mi < 4; ++mi)
#pragma unroll
            for (int ni = 0; ni < 4; ++ni)
                acc[mi][ni] = __builtin_amdgcn_mfma_f32_16x16x32_bf16(
                    af[mi], bfv[ni], acc[mi][ni], 0, 0, 0);
        __builtin_amdgcn_s_setprio(0);
        __builtin_amdgcn_s_barrier();

        // ---- P3: quadrant (mi 4-7, kk1) ----
#pragma unroll
        for (int mi = 0; mi < 4; ++mi)
            af[mi] = *(const bf16x8*)(Ab + 8192 + (4 + mi) * 512);
        if (k <= 61) STAGE_B(k + 2, 1);
        if (k <= 61)
            asm volatile("s_waitcnt vmcnt(6)" ::: "memory"); // tile k+1 landed
        else
            asm volatile("s_waitcnt vmcnt(0)" ::: "memory");
        PHASE_SYNC();
        __builtin_amdgcn_s_setprio(1);
#pragma unroll
        for (int mi = 0; mi < 4; ++mi)
#pragma unroll
            for (int ni = 0; ni < 4; ++ni)
                acc[4 + mi][ni] = __builtin_amdgcn_mfma_f32_16x16x32_bf16(
                    af[mi], bfv[ni], acc[4 + mi][ni], 0, 0, 0);
        __builtin_amdgcn_s_setprio(0);
        __builtin_amdgcn_s_barrier();
    }
#undef STAGE_A
#undef STAGE_B
#undef PHASE_SYNC

    // Fused LSTM epilogue — each lane's frag = (i,f,o,n~) for one (b,u)
#pragma unroll
    for (int mi = 0; mi < 8; ++mi) {
        const int u = ((m_base + wm + mi * 16) >> 2) + lq;
#pragma unroll
        for (int ni = 0; ni < 4; ++ni) {
            const int b = n_base + wn + ni * 16 + l15;
            f32x4 gv = acc[mi][ni];
            float i_t = fast_sigmoid(gv[0]);
            float f_t = fast_sigmoid(gv[1]);
            float o_t = fast_sigmoid(gv[2]);
            float n_t = fast_tanh(gv[3]);
            float pc  = pre_c[(size_t)b * UNITS_DIM + u];
            float c   = f_t * pc + i_t * n_t;
            float h   = o_t * fast_tanh(c);
            out[(size_t)b * UNITS_DIM + u] = h;
            out[(size_t)B_DIM * UNITS_DIM + (size_t)b * UNITS_DIM + u] = c;
        }
    }
}

extern "C" void kernel_launch(void* const* d_in, const int* in_sizes, int n_in,
                              void* d_out, int out_size, void* d_ws, size_t ws_size,
                              hipStream_t stream) {
    const float* pre_layer = (const float*)d_in[0];   // (2, 4096, 2048)
    const float* x         = (const float*)d_in[1];   // (4096, 2048)
    const float* W         = (const float*)d_in[2];   // (4, 2048, 2048)
    const float* U         = (const float*)d_in[3];   // (4, 2048, 2048)
    float* out = (float*)d_out;

    const float* pre_h = pre_layer;
    const float* pre_c = pre_layer + (size_t)B_DIM * UNITS_DIM;

    __hip_bfloat16* Abf = (__hip_bfloat16*)d_ws;                       // 32 MiB
    __hip_bfloat16* Bbf = (__hip_bfloat16*)((char*)d_ws +
                          (size_t)B_DIM * K_DIM * sizeof(__hip_bfloat16)); // 64 MiB

    convert_act<<<8192, 256, 0, stream>>>(pre_h, x, Abf);
    convert_wu<<<16384, 256, 0, stream>>>(W, U, Bbf);

    lstm_gemm<<<512, 512, 0, stream>>>(Bbf, Abf, pre_c, out);
}

// Round 5
// 491.633 us; speedup vs baseline: 1.3067x; 1.3067x over previous
//
#include <hip/hip_runtime.h>
#include <hip/hip_bf16.h>

#define B_DIM 4096
#define UNITS_DIM 2048
#define K_DIM 4096   // INP + UNITS concatenated
#define M_DIM 8192   // 4 gates * UNITS, interleaved n = u*4 + g

typedef __bf16 bf16x8 __attribute__((ext_vector_type(8)));
typedef float f32x4 __attribute__((ext_vector_type(4)));

#define AS1C(p) ((const __attribute__((address_space(1))) void*)(p))
#define AS3(p)  ((__attribute__((address_space(3))) void*)(p))

__device__ __forceinline__ float fast_sigmoid(float x) {
    return 1.0f / (1.0f + __expf(-x));
}
__device__ __forceinline__ float fast_tanh(float x) {
    return 2.0f / (1.0f + __expf(-2.0f * x)) - 1.0f;
}

// ---------------------------------------------------------------------------
// Fused convert kernel (one launch). Grid-stride over both jobs:
//   chunks [0, NA):            Abf[b][k] = bf16( k<2048 ? x[b][k] : pre_h[...] )
//   chunks [NA, NA+NB):        Bbf[n][k] = bf16( k<2048 ? W[g][u][k] : U[...] ),
//                              n = u*4 + g
// fp32 sources are read ONCE -> nontemporal loads (via native ext-vector
// type; HIP float4 is a struct and is rejected by the builtin) so they do
// not evict the bf16 workspace (which lstm_gemm re-reads from L3).
// 2048 blocks x 256 threads x 12 iters covers all 6,291,456 8-elem chunks.
// ---------------------------------------------------------------------------
#define NA_CHUNKS (((long long)B_DIM * K_DIM) / 8)        // 2,097,152
#define NB_CHUNKS (((long long)M_DIM * K_DIM) / 8)        // 4,194,304

__global__ __launch_bounds__(256) void convert_fused(
    const float* __restrict__ pre_h,
    const float* __restrict__ x,
    const float* __restrict__ W,
    const float* __restrict__ U,
    __hip_bfloat16* __restrict__ Abf,
    __hip_bfloat16* __restrict__ Bbf) {
    const long long stride = (long long)gridDim.x * blockDim.x;
    for (long long i = (long long)blockIdx.x * blockDim.x + threadIdx.x;
         i < NA_CHUNKS + NB_CHUNKS; i += stride) {
        const float* src;
        __hip_bfloat16* dst;
        if (i < NA_CHUNKS) {
            const long long e = i * 8;
            const int b = (int)(e >> 12);
            const int k = (int)(e & 4095);
            src = (k < UNITS_DIM)
                ? (x + (long long)b * UNITS_DIM + k)
                : (pre_h + (long long)b * UNITS_DIM + (k - UNITS_DIM));
            dst = Abf + e;
        } else {
            const long long e = (i - NA_CHUNKS) * 8;
            const int n = (int)(e >> 12);
            const int k = (int)(e & 4095);
            const int u = n >> 2;
            const int g = n & 3;
            src = (k < UNITS_DIM)
                ? (W + ((long long)g * UNITS_DIM + u) * UNITS_DIM + k)
                : (U + ((long long)g * UNITS_DIM + u) * UNITS_DIM + (k - UNITS_DIM));
            dst = Bbf + e;
        }
        f32x4 f0 = __builtin_nontemporal_load((const f32x4*)src);
        f32x4 f1 = __builtin_nontemporal_load(((const f32x4*)src) + 1);
        union { __hip_bfloat16 h[8]; uint4 u4; } p;
        p.h[0] = __float2bfloat16(f0[0]); p.h[1] = __float2bfloat16(f0[1]);
        p.h[2] = __float2bfloat16(f0[2]); p.h[3] = __float2bfloat16(f0[3]);
        p.h[4] = __float2bfloat16(f1[0]); p.h[5] = __float2bfloat16(f1[1]);
        p.h[6] = __float2bfloat16(f1[2]); p.h[7] = __float2bfloat16(f1[3]);
        *(uint4*)dst = p.u4;
    }
}

// ---------------------------------------------------------------------------
// Kernel 3 (verified round-0 version, 322 us / 860 TF):
// 128x128-tile bt-GEMM with XOR-swizzled LDS + fused LSTM epilogue.
//   Row stride in LDS is 64 bf16 = 32 dwords == 0 mod 32 banks, so the naive
//   layout gives 16-way conflicts on every ds_read_b128. global_load_lds
//   forbids per-lane LDS scatter, so we permute the GLOBAL chunk each lane
//   fetches:  LDS chunk c of row r holds global chunk  c ^ (r & 7).
//   Readers of (row r, global chunk g) index LDS chunk g ^ (r&7); each
//   16-lane quad-group then covers all 8 chunk-columns twice -> 2-way
//   aliasing, which is free (m136). Measured SQ_LDS_BANK_CONFLICT = 0.
//   Full 128-B rows are staged per half-tile -> no cache-line splitting,
//   steady-state operands stay L3-resident (~85 MB HBM fetch/iter).
// ---------------------------------------------------------------------------
__global__ __launch_bounds__(256, 3) void lstm_gemm(
    const __hip_bfloat16* __restrict__ Wc,   // 8192 x 4096 (A operand)
    const __hip_bfloat16* __restrict__ Ac,   // 4096 x 4096 (B operand)
    const float* __restrict__ pre_c,         // 4096 x 2048
    float* __restrict__ out)                 // (2, 4096, 2048)
{
    __shared__ __hip_bfloat16 As[128 * 64];
    __shared__ __hip_bfloat16 Bs[128 * 64];

    const int tid  = threadIdx.x;
    const int lane = tid & 63;
    const int wave = tid >> 6;
    const int m_base = blockIdx.x * 128;
    const int n_base = blockIdx.y * 128;
    const int wm = (wave >> 1) * 64;
    const int wn = (wave & 1) * 64;
    const int l15 = lane & 15;
    const int lq  = lane >> 4;
    const int x7  = l15 & 7;            // read-side swizzle key (row & 7)

    f32x4 acc[4][4] = {};

    // staging: thread t -> row = t>>3 (+32/round), LDS chunk c = t&7.
    // Fetch global chunk c ^ (row&7) so LDS layout is XOR-swizzled.
    const int srow = tid >> 3;
    const int scol = (((tid & 7) ^ (srow & 7)) * 8);   // swizzled global col
    const __hip_bfloat16* wg = Wc + (size_t)(m_base + srow) * K_DIM + scol;
    const __hip_bfloat16* ag = Ac + (size_t)(n_base + srow) * K_DIM + scol;

    for (int k0 = 0; k0 < K_DIM; k0 += 64) {
#pragma unroll
        for (int r = 0; r < 4; ++r) {
            __builtin_amdgcn_global_load_lds(
                AS1C(wg + (size_t)(r * 32) * K_DIM + k0),
                AS3(As + r * 2048 + tid * 8), 16, 0, 0);
            __builtin_amdgcn_global_load_lds(
                AS1C(ag + (size_t)(r * 32) * K_DIM + k0),
                AS3(Bs + r * 2048 + tid * 8), 16, 0, 0);
        }
        __syncthreads();
#pragma unroll
        for (int ki = 0; ki < 2; ++ki) {
            const int ca = ((ki * 4 + lq) ^ x7) * 8;   // swizzled LDS chunk
            bf16x8 af[4], bfr[4];
#pragma unroll
            for (int mi = 0; mi < 4; ++mi)
                af[mi] = *(const bf16x8*)(As + (wm + mi * 16 + l15) * 64 + ca);
#pragma unroll
            for (int ni = 0; ni < 4; ++ni)
                bfr[ni] = *(const bf16x8*)(Bs + (wn + ni * 16 + l15) * 64 + ca);
#pragma unroll
            for (int mi = 0; mi < 4; ++mi)
#pragma unroll
                for (int ni = 0; ni < 4; ++ni)
                    acc[mi][ni] = __builtin_amdgcn_mfma_f32_16x16x32_bf16(
                        af[mi], bfr[ni], acc[mi][ni], 0, 0, 0);
        }
        __syncthreads();
    }

    // Fused LSTM epilogue — each lane's frag = (i,f,o,n~) for one (b,u)
#pragma unroll
    for (int mi = 0; mi < 4; ++mi) {
        const int u = ((m_base + wm + mi * 16) >> 2) + lq;
#pragma unroll
        for (int ni = 0; ni < 4; ++ni) {
            const int b = n_base + wn + ni * 16 + l15;
            f32x4 gv = acc[mi][ni];
            float i_t = fast_sigmoid(gv[0]);
            float f_t = fast_sigmoid(gv[1]);
            float o_t = fast_sigmoid(gv[2]);
            float n_t = fast_tanh(gv[3]);
            float pc  = pre_c[(size_t)b * UNITS_DIM + u];
            float c   = f_t * pc + i_t * n_t;
            float h   = o_t * fast_tanh(c);
            out[(size_t)b * UNITS_DIM + u] = h;
            out[(size_t)B_DIM * UNITS_DIM + (size_t)b * UNITS_DIM + u] = c;
        }
    }
}

extern "C" void kernel_launch(void* const* d_in, const int* in_sizes, int n_in,
                              void* d_out, int out_size, void* d_ws, size_t ws_size,
                              hipStream_t stream) {
    const float* pre_layer = (const float*)d_in[0];   // (2, 4096, 2048)
    const float* x         = (const float*)d_in[1];   // (4096, 2048)
    const float* W         = (const float*)d_in[2];   // (4, 2048, 2048)
    const float* U         = (const float*)d_in[3];   // (4, 2048, 2048)
    float* out = (float*)d_out;

    const float* pre_h = pre_layer;
    const float* pre_c = pre_layer + (size_t)B_DIM * UNITS_DIM;

    __hip_bfloat16* Abf = (__hip_bfloat16*)d_ws;                       // 32 MiB
    __hip_bfloat16* Bbf = (__hip_bfloat16*)((char*)d_ws +
                          (size_t)B_DIM * K_DIM * sizeof(__hip_bfloat16)); // 64 MiB

    convert_fused<<<2048, 256, 0, stream>>>(pre_h, x, W, U, Abf, Bbf);

    dim3 grid(M_DIM / 128, B_DIM / 128);   // (64, 32)
    lstm_gemm<<<grid, 256, 0, stream>>>(Bbf, Abf, pre_c, out);
}

// Round 6
// 488.818 us; speedup vs baseline: 1.3142x; 1.0058x over previous
//
#include <hip/hip_runtime.h>
#include <hip/hip_bf16.h>

#define B_DIM 4096
#define UNITS_DIM 2048
#define K_DIM 4096   // INP + UNITS concatenated
#define M_DIM 8192   // 4 gates * UNITS, interleaved n = u*4 + g

typedef __bf16 bf16x8 __attribute__((ext_vector_type(8)));
typedef float f32x4 __attribute__((ext_vector_type(4)));

#define AS1C(p) ((const __attribute__((address_space(1))) void*)(p))
#define AS3(p)  ((__attribute__((address_space(3))) void*)(p))

__device__ __forceinline__ float fast_sigmoid(float x) {
    return 1.0f / (1.0f + __expf(-x));
}
__device__ __forceinline__ float fast_tanh(float x) {
    return 2.0f / (1.0f + __expf(-2.0f * x)) - 1.0f;
}

// ---------------------------------------------------------------------------
// Fused convert kernel, FLAT (one 8-elem chunk per thread, no loop):
//   blocks [0, 8192):      Abf[b][k] = bf16( k<2048 ? x[b][k] : pre_h[...] )
//   blocks [8192, 24576):  Bbf[n][k] = bf16( k<2048 ? W[g][u][k] : U[...] ),
//                          n = u*4 + g
// The job split is block-uniform (8192*256 == NA_CHUNKS) -> no lane
// divergence. fp32 sources are read ONCE -> nontemporal loads so they do
// not evict the bf16 workspace (lstm_gemm re-reads it from L2/L3; measured
// GEMM FETCH 582->375 MB when NT was introduced). Stores stay cached.
// Flat 1:1 mapping maximizes outstanding loads per SIMD vs the previous
// 12-iteration grid-stride loop (suspected MLP limiter: ~1.6 TB/s).
// ---------------------------------------------------------------------------
#define NA_CHUNKS (((long long)B_DIM * K_DIM) / 8)        // 2,097,152
#define NB_CHUNKS (((long long)M_DIM * K_DIM) / 8)        // 4,194,304

__global__ __launch_bounds__(256) void convert_fused(
    const float* __restrict__ pre_h,
    const float* __restrict__ x,
    const float* __restrict__ W,
    const float* __restrict__ U,
    __hip_bfloat16* __restrict__ Abf,
    __hip_bfloat16* __restrict__ Bbf) {
    const float* src;
    __hip_bfloat16* dst;
    if (blockIdx.x < 8192) {                       // A job (block-uniform)
        const long long e = ((long long)blockIdx.x * 256 + threadIdx.x) * 8;
        const int b = (int)(e >> 12);
        const int k = (int)(e & 4095);
        src = (k < UNITS_DIM)
            ? (x + (long long)b * UNITS_DIM + k)
            : (pre_h + (long long)b * UNITS_DIM + (k - UNITS_DIM));
        dst = Abf + e;
    } else {                                       // B job
        const long long e = ((long long)(blockIdx.x - 8192) * 256 + threadIdx.x) * 8;
        const int n = (int)(e >> 12);
        const int k = (int)(e & 4095);
        const int u = n >> 2;
        const int g = n & 3;
        src = (k < UNITS_DIM)
            ? (W + ((long long)g * UNITS_DIM + u) * UNITS_DIM + k)
            : (U + ((long long)g * UNITS_DIM + u) * UNITS_DIM + (k - UNITS_DIM));
        dst = Bbf + e;
    }
    f32x4 f0 = __builtin_nontemporal_load((const f32x4*)src);
    f32x4 f1 = __builtin_nontemporal_load(((const f32x4*)src) + 1);
    union { __hip_bfloat16 h[8]; uint4 u4; } p;
    p.h[0] = __float2bfloat16(f0[0]); p.h[1] = __float2bfloat16(f0[1]);
    p.h[2] = __float2bfloat16(f0[2]); p.h[3] = __float2bfloat16(f0[3]);
    p.h[4] = __float2bfloat16(f1[0]); p.h[5] = __float2bfloat16(f1[1]);
    p.h[6] = __float2bfloat16(f1[2]); p.h[7] = __float2bfloat16(f1[3]);
    *(uint4*)dst = p.u4;
}

// ---------------------------------------------------------------------------
// Kernel 3 (verified, 301 us / ~915 TF this harness, MfmaUtil 41%):
// 128x128-tile bt-GEMM with XOR-swizzled LDS + fused LSTM epilogue.
//   Row stride in LDS is 64 bf16 = 32 dwords == 0 mod 32 banks, so the naive
//   layout gives 16-way conflicts on every ds_read_b128. global_load_lds
//   forbids per-lane LDS scatter, so we permute the GLOBAL chunk each lane
//   fetches:  LDS chunk c of row r holds global chunk  c ^ (r & 7).
//   Readers of (row r, global chunk g) index LDS chunk g ^ (r&7); each
//   16-lane quad-group then covers all 8 chunk-columns twice -> 2-way
//   aliasing, which is free (m136). Measured SQ_LDS_BANK_CONFLICT = 0.
//   DO NOT restructure the K-loop: two 256-tile deep-pipeline attempts
//   (R1 ring-4, R2 8-phase with 32-col slabs) both regressed (-10%/-25%).
// ---------------------------------------------------------------------------
__global__ __launch_bounds__(256, 3) void lstm_gemm(
    const __hip_bfloat16* __restrict__ Wc,   // 8192 x 4096 (A operand)
    const __hip_bfloat16* __restrict__ Ac,   // 4096 x 4096 (B operand)
    const float* __restrict__ pre_c,         // 4096 x 2048
    float* __restrict__ out)                 // (2, 4096, 2048)
{
    __shared__ __hip_bfloat16 As[128 * 64];
    __shared__ __hip_bfloat16 Bs[128 * 64];

    const int tid  = threadIdx.x;
    const int lane = tid & 63;
    const int wave = tid >> 6;
    const int m_base = blockIdx.x * 128;
    const int n_base = blockIdx.y * 128;
    const int wm = (wave >> 1) * 64;
    const int wn = (wave & 1) * 64;
    const int l15 = lane & 15;
    const int lq  = lane >> 4;
    const int x7  = l15 & 7;            // read-side swizzle key (row & 7)

    f32x4 acc[4][4] = {};

    // staging: thread t -> row = t>>3 (+32/round), LDS chunk c = t&7.
    // Fetch global chunk c ^ (row&7) so LDS layout is XOR-swizzled.
    const int srow = tid >> 3;
    const int scol = (((tid & 7) ^ (srow & 7)) * 8);   // swizzled global col
    const __hip_bfloat16* wg = Wc + (size_t)(m_base + srow) * K_DIM + scol;
    const __hip_bfloat16* ag = Ac + (size_t)(n_base + srow) * K_DIM + scol;

    for (int k0 = 0; k0 < K_DIM; k0 += 64) {
#pragma unroll
        for (int r = 0; r < 4; ++r) {
            __builtin_amdgcn_global_load_lds(
                AS1C(wg + (size_t)(r * 32) * K_DIM + k0),
                AS3(As + r * 2048 + tid * 8), 16, 0, 0);
            __builtin_amdgcn_global_load_lds(
                AS1C(ag + (size_t)(r * 32) * K_DIM + k0),
                AS3(Bs + r * 2048 + tid * 8), 16, 0, 0);
        }
        __syncthreads();
#pragma unroll
        for (int ki = 0; ki < 2; ++ki) {
            const int ca = ((ki * 4 + lq) ^ x7) * 8;   // swizzled LDS chunk
            bf16x8 af[4], bfr[4];
#pragma unroll
            for (int mi = 0; mi < 4; ++mi)
                af[mi] = *(const bf16x8*)(As + (wm + mi * 16 + l15) * 64 + ca);
#pragma unroll
            for (int ni = 0; ni < 4; ++ni)
                bfr[ni] = *(const bf16x8*)(Bs + (wn + ni * 16 + l15) * 64 + ca);
#pragma unroll
            for (int mi = 0; mi < 4; ++mi)
#pragma unroll
                for (int ni = 0; ni < 4; ++ni)
                    acc[mi][ni] = __builtin_amdgcn_mfma_f32_16x16x32_bf16(
                        af[mi], bfr[ni], acc[mi][ni], 0, 0, 0);
        }
        __syncthreads();
    }

    // Fused LSTM epilogue — each lane's frag = (i,f,o,n~) for one (b,u)
#pragma unroll
    for (int mi = 0; mi < 4; ++mi) {
        const int u = ((m_base + wm + mi * 16) >> 2) + lq;
#pragma unroll
        for (int ni = 0; ni < 4; ++ni) {
            const int b = n_base + wn + ni * 16 + l15;
            f32x4 gv = acc[mi][ni];
            float i_t = fast_sigmoid(gv[0]);
            float f_t = fast_sigmoid(gv[1]);
            float o_t = fast_sigmoid(gv[2]);
            float n_t = fast_tanh(gv[3]);
            float pc  = pre_c[(size_t)b * UNITS_DIM + u];
            float c   = f_t * pc + i_t * n_t;
            float h   = o_t * fast_tanh(c);
            out[(size_t)b * UNITS_DIM + u] = h;
            out[(size_t)B_DIM * UNITS_DIM + (size_t)b * UNITS_DIM + u] = c;
        }
    }
}

extern "C" void kernel_launch(void* const* d_in, const int* in_sizes, int n_in,
                              void* d_out, int out_size, void* d_ws, size_t ws_size,
                              hipStream_t stream) {
    const float* pre_layer = (const float*)d_in[0];   // (2, 4096, 2048)
    const float* x         = (const float*)d_in[1];   // (4096, 2048)
    const float* W         = (const float*)d_in[2];   // (4, 2048, 2048)
    const float* U         = (const float*)d_in[3];   // (4, 2048, 2048)
    float* out = (float*)d_out;

    const float* pre_h = pre_layer;
    const float* pre_c = pre_layer + (size_t)B_DIM * UNITS_DIM;

    __hip_bfloat16* Abf = (__hip_bfloat16*)d_ws;                       // 32 MiB
    __hip_bfloat16* Bbf = (__hip_bfloat16*)((char*)d_ws +
                          (size_t)B_DIM * K_DIM * sizeof(__hip_bfloat16)); // 64 MiB

    convert_fused<<<24576, 256, 0, stream>>>(pre_h, x, W, U, Abf, Bbf);

    dim3 grid(M_DIM / 128, B_DIM / 128);   // (64, 32)
    lstm_gemm<<<grid, 256, 0, stream>>>(Bbf, Abf, pre_c, out);
}